// Round 1
// baseline (25.303 us; speedup 1.0000x reference)
//
#include <hip/hip_runtime.h>
#include <math.h>

#define HH 256
#define WW 256
#define CC 32
#define NN 4
#define ROWS 16
#define STRIPS (HH / ROWS)   // 16

// ---------------- Kernel 1: per-plane mean pool ----------------
__global__ __launch_bounds__(256) void pool_kernel(const float* __restrict__ x,
                                                   float* __restrict__ pooled) {
    const int plane = blockIdx.x;  // n*32 + c, 0..127
    const float4* xb = (const float4*)(x + (size_t)plane * HH * WW);
    const int t = threadIdx.x;
    float s = 0.f;
    // 65536 floats = 16384 float4; 256 threads -> 64 iters each
    #pragma unroll 4
    for (int i = t; i < (HH * WW) / 4; i += 256) {
        float4 v = xb[i];
        s += (v.x + v.y) + (v.z + v.w);
    }
    // wave64 reduce
    #pragma unroll
    for (int off = 32; off > 0; off >>= 1)
        s += __shfl_down(s, off, 64);
    __shared__ float wsum[4];
    const int lane = t & 63, wid = t >> 6;
    if (lane == 0) wsum[wid] = s;
    __syncthreads();
    if (t == 0) {
        float tot = (wsum[0] + wsum[1]) + (wsum[2] + wsum[3]);
        pooled[plane] = tot * (1.0f / (HH * WW));
    }
}

// ---------------- Kernel 2: dynamic filter + stencil + affine ----------------
__global__ __launch_bounds__(256) void dynfilt_kernel(
    const float* __restrict__ x,
    const float* __restrict__ conv_w,
    const float* __restrict__ bn_gamma, const float* __restrict__ bn_beta,
    const float* __restrict__ bn_mean, const float* __restrict__ bn_var,
    const float* __restrict__ lamb_l, const float* __restrict__ lamb_h,
    const float* __restrict__ inside_all,
    const float* __restrict__ pooled,
    float* __restrict__ out)
{
    __shared__ float tile[ROWS + 2][WW];
    __shared__ float sfilt[9];
    __shared__ float scoef[3];

    const int bid   = blockIdx.x;
    const int strip = bid & (STRIPS - 1);
    const int plane = bid >> 4;          // STRIPS == 16
    const int n = plane >> 5;            // CC == 32
    const int c = plane & 31;
    const int g = c >> 2;                // c / (C/G) = c/4
    const int t = threadIdx.x;

    // --- tiny per-block scalar phase: filter taps + affine coefs ---
    if (t < 9) {
        const int j = g * 9 + t;
        const float* wrow = conv_w + (size_t)j * CC;
        const float* pn = pooled + n * CC;
        float f = 0.f;
        #pragma unroll
        for (int i = 0; i < CC; ++i) f += pn[i] * wrow[i];
        f = (f - bn_mean[j]) * bn_gamma[j] * rsqrtf(bn_var[j] + 1e-5f) + bn_beta[j];
        sfilt[t] = tanhf(f);
    } else if (t == 9) {
        const float ia = inside_all[c];
        const float ll = lamb_l[c];
        scoef[0] = (ia + 1.0f) * ll;                  // cA
        scoef[1] = -ia * pooled[n * CC + c] * ll;     // cB
        scoef[2] = lamb_h[c] + 1.0f;                  // cC
    }

    // --- stage 18 rows (with row reflection) into LDS via float4 ---
    const float* xp = x + (size_t)plane * HH * WW;
    const int r0 = strip * ROWS;
    for (int idx = t; idx < (ROWS + 2) * (WW / 4); idx += 256) {
        const int row  = idx >> 6;     // / (WW/4)
        const int col4 = idx & 63;
        int gr = r0 - 1 + row;
        gr = (gr < 0) ? -gr : ((gr >= HH) ? (2 * HH - 2 - gr) : gr);
        const float4 v = *(const float4*)(xp + (size_t)gr * WW + col4 * 4);
        *(float4*)(&tile[row][col4 * 4]) = v;
    }
    __syncthreads();

    const float f0 = sfilt[0], f1 = sfilt[1], f2 = sfilt[2];
    const float f3 = sfilt[3], f4 = sfilt[4], f5 = sfilt[5];
    const float f6 = sfilt[6], f7 = sfilt[7], f8 = sfilt[8];
    const float cA = scoef[0], cB = scoef[1], cC = scoef[2];

    // column reflection (only columns 0 and 255 reflect)
    const int lt = (t == 0)      ? 1       : t - 1;
    const int rt = (t == WW - 1) ? WW - 2  : t + 1;

    // 3-row sliding register window down this thread's column
    float wl[3], wc[3], wr[3];
    wl[0] = tile[0][lt]; wc[0] = tile[0][t]; wr[0] = tile[0][rt];
    wl[1] = tile[1][lt]; wc[1] = tile[1][t]; wr[1] = tile[1][rt];

    float* op = out + (size_t)plane * HH * WW + (size_t)r0 * WW + t;
    #pragma unroll
    for (int rr = 0; rr < ROWS; ++rr) {
        const int i0 = rr % 3, i1 = (rr + 1) % 3, i2 = (rr + 2) % 3;
        wl[i2] = tile[rr + 2][lt];
        wc[i2] = tile[rr + 2][t];
        wr[i2] = tile[rr + 2][rt];
        const float s = f0 * wl[i0] + f1 * wc[i0] + f2 * wr[i0]
                      + f3 * wl[i1] + f4 * wc[i1] + f5 * wr[i1]
                      + f6 * wl[i2] + f7 * wc[i2] + f8 * wr[i2];
        op[(size_t)rr * WW] = cA * s + cB + cC * wc[i1];
    }
}

extern "C" void kernel_launch(void* const* d_in, const int* in_sizes, int n_in,
                              void* d_out, int out_size, void* d_ws, size_t ws_size,
                              hipStream_t stream) {
    const float* x          = (const float*)d_in[0];
    const float* conv_w     = (const float*)d_in[1];
    const float* bn_gamma   = (const float*)d_in[2];
    const float* bn_beta    = (const float*)d_in[3];
    const float* bn_mean    = (const float*)d_in[4];
    const float* bn_var     = (const float*)d_in[5];
    const float* lamb_l     = (const float*)d_in[6];
    const float* lamb_h     = (const float*)d_in[7];
    const float* inside_all = (const float*)d_in[8];
    float* out    = (float*)d_out;
    float* pooled = (float*)d_ws;   // 128 floats

    hipLaunchKernelGGL(pool_kernel, dim3(NN * CC), dim3(256), 0, stream, x, pooled);
    hipLaunchKernelGGL(dynfilt_kernel, dim3(NN * CC * STRIPS), dim3(256), 0, stream,
                       x, conv_w, bn_gamma, bn_beta, bn_mean, bn_var,
                       lamb_l, lamb_h, inside_all, pooled, out);
}